// Round 1
// baseline (7078.743 us; speedup 1.0000x reference)
//
#include <hip/hip_runtime.h>

static constexpr int KDIM   = 128;   // input feature dim of every layer
static constexpr int NEDGES = 20000;

// ---------------- GEMM: P[N,NO] = H[N,128] @ W[128,NO] ----------------
// One thread per output row; W staged in LDS, read with wave-uniform
// (broadcast, conflict-free) addresses. 32 f32 accumulators per col-block.
template<int NO>
__global__ __launch_bounds__(256) void gemm_rows(const float* __restrict__ H,
                                                 const float* __restrict__ W,
                                                 float* __restrict__ P, int N) {
    __shared__ float Wl[KDIM * NO];
    for (int i = threadIdx.x; i < KDIM * NO; i += 256) Wl[i] = W[i];
    __syncthreads();
    int row = blockIdx.x * 256 + threadIdx.x;
    if (row >= N) return;
    const float* xr = H + (size_t)row * KDIM;
    float* pr = P + (size_t)row * NO;
#pragma unroll
    for (int cb = 0; cb < NO / 32; ++cb) {
        float acc[32];
#pragma unroll
        for (int j = 0; j < 32; ++j) acc[j] = 0.0f;
        for (int k4 = 0; k4 < KDIM / 4; ++k4) {
            const float4 xv = *reinterpret_cast<const float4*>(xr + k4 * 4);
            const float xs[4] = {xv.x, xv.y, xv.z, xv.w};
#pragma unroll
            for (int kk = 0; kk < 4; ++kk) {
                const float* wrow = &Wl[(k4 * 4 + kk) * NO + cb * 32];
#pragma unroll
                for (int j = 0; j < 32; ++j) acc[j] = fmaf(xs[kk], wrow[j], acc[j]);
            }
        }
#pragma unroll
        for (int j = 0; j < 32; j += 4) {
            float4 o;
            o.x = acc[j]; o.y = acc[j + 1]; o.z = acc[j + 2]; o.w = acc[j + 3];
            *reinterpret_cast<float4*>(pr + cb * 32 + j) = o;
        }
    }
}

// ---------------- edge-size histogram (float counts) ----------------
__global__ void count_kernel(const int* __restrict__ edges, float* __restrict__ cnt, int nnz) {
    int i = blockIdx.x * blockDim.x + threadIdx.x;
    if (i < nnz) unsafeAtomicAdd(&cnt[edges[i]], 1.0f);
}

__global__ void inv_kernel(float* __restrict__ cntinv, int E) {
    int i = blockIdx.x * blockDim.x + threadIdx.x;
    if (i < E) cntinv[i] = 1.0f / fmaxf(cntinv[i], 1.0f);
}

// ---------------- vertex -> edge scatter: C[edges[i]] += P[vertex[i]] ----------------
template<int NO>
__global__ __launch_bounds__(256) void scatter_ve(const float* __restrict__ P,
                                                  const int* __restrict__ vertex,
                                                  const int* __restrict__ edges,
                                                  float* __restrict__ C, int nnz) {
    constexpr int LPE = NO / 4;              // lanes per entry (float4 each)
    int tid = blockIdx.x * 256 + threadIdx.x;
    int entry = tid / LPE;
    if (entry >= nnz) return;
    int l = tid % LPE;
    int v = vertex[entry];
    int e = edges[entry];
    const float4 x = *reinterpret_cast<const float4*>(P + (size_t)v * NO + l * 4);
    float* dst = C + (size_t)e * NO + l * 4;
    unsafeAtomicAdd(dst + 0, x.x);
    unsafeAtomicAdd(dst + 1, x.y);
    unsafeAtomicAdd(dst + 2, x.z);
    unsafeAtomicAdd(dst + 3, x.w);
}

// ---------------- edge -> vertex scatter: D[vertex[i]] += C[edges[i]] * inv[edges[i]] ----------------
template<int NO>
__global__ __launch_bounds__(256) void scatter_ev(const float* __restrict__ C,
                                                  const float* __restrict__ inv,
                                                  const int* __restrict__ vertex,
                                                  const int* __restrict__ edges,
                                                  float* __restrict__ D, int nnz) {
    constexpr int LPE = NO / 4;
    int tid = blockIdx.x * 256 + threadIdx.x;
    int entry = tid / LPE;
    if (entry >= nnz) return;
    int l = tid % LPE;
    int v = vertex[entry];
    int e = edges[entry];
    float s = inv[e];
    const float4 x = *reinterpret_cast<const float4*>(C + (size_t)e * NO + l * 4);
    float* dst = D + (size_t)v * NO + l * 4;
    unsafeAtomicAdd(dst + 0, x.x * s);
    unsafeAtomicAdd(dst + 1, x.y * s);
    unsafeAtomicAdd(dst + 2, x.z * s);
    unsafeAtomicAdd(dst + 3, x.w * s);
}

// ---------------- combine: out = relu?((1+eps)*P + D) ----------------
template<bool RELU>
__global__ __launch_bounds__(256) void combine4(const float4* __restrict__ P,
                                                const float4* __restrict__ D,
                                                const float* __restrict__ eps,
                                                float4* __restrict__ out, int n4) {
    int i = blockIdx.x * 256 + threadIdx.x;
    if (i >= n4) return;
    float g = 1.0f + eps[0];
    float4 p = P[i], d = D[i], o;
    o.x = g * p.x + d.x;
    o.y = g * p.y + d.y;
    o.z = g * p.z + d.z;
    o.w = g * p.w + d.w;
    if (RELU) {
        o.x = fmaxf(o.x, 0.0f); o.y = fmaxf(o.y, 0.0f);
        o.z = fmaxf(o.z, 0.0f); o.w = fmaxf(o.w, 0.0f);
    }
    out[i] = o;
}

// ---------------- Xe output (layer 3): out = C * inv, NO = 64 ----------------
__global__ __launch_bounds__(256) void xeout_kernel(const float* __restrict__ C,
                                                    const float* __restrict__ inv,
                                                    float* __restrict__ out, int total) {
    int i = blockIdx.x * 256 + threadIdx.x;
    if (i >= total) return;
    out[i] = C[i] * inv[i >> 6];   // NO = 64
}

extern "C" void kernel_launch(void* const* d_in, const int* in_sizes, int n_in,
                              void* d_out, int out_size, void* d_ws, size_t ws_size,
                              hipStream_t stream) {
    const float* X      = (const float*)d_in[0];
    const int*   vertex = (const int*)d_in[1];
    const int*   edges  = (const int*)d_in[2];
    const float* W1     = (const float*)d_in[3];
    const float* W2     = (const float*)d_in[4];
    const float* W3     = (const float*)d_in[5];
    const float* eps1   = (const float*)d_in[6];
    const float* eps2   = (const float*)d_in[7];
    const float* eps3   = (const float*)d_in[8];

    const int N   = in_sizes[0] / KDIM;   // 100000
    const int nnz = in_sizes[1];          // 800000
    const int E   = NEDGES;               // 20000

    char* ws = (char*)d_ws;
    float* bufP = (float*)ws;                                   // N*128 f32
    float* bufD = (float*)(ws + (size_t)N * KDIM * 4);          // N*128 f32 (doubles as h)
    float* bufC = (float*)(ws + (size_t)N * KDIM * 4 * 2);      // E*128 f32
    float* inv  = (float*)(ws + (size_t)N * KDIM * 4 * 2 + (size_t)E * KDIM * 4); // E f32

    float* outV = (float*)d_out;                 // N*64
    float* outE = outV + (size_t)N * 64;         // E*64

    const int TPB = 256;
    auto blocks = [](long long t) { return (unsigned)((t + 255) / 256); };

    // edge counts + reciprocals (layer-invariant, computed once per call)
    hipMemsetAsync(inv, 0, (size_t)E * sizeof(float), stream);
    count_kernel<<<blocks(nnz), TPB, 0, stream>>>(edges, inv, nnz);
    inv_kernel<<<blocks(E), TPB, 0, stream>>>(inv, E);

    // ---------------- layer 1: X[ N,128] -> h1 in bufD ----------------
    gemm_rows<128><<<blocks(N), TPB, 0, stream>>>(X, W1, bufP, N);
    hipMemsetAsync(bufC, 0, (size_t)E * 128 * 4, stream);
    scatter_ve<128><<<blocks((long long)nnz * 32), TPB, 0, stream>>>(bufP, vertex, edges, bufC, nnz);
    hipMemsetAsync(bufD, 0, (size_t)N * 128 * 4, stream);
    scatter_ev<128><<<blocks((long long)nnz * 32), TPB, 0, stream>>>(bufC, inv, vertex, edges, bufD, nnz);
    combine4<true><<<blocks((long long)N * 128 / 4), TPB, 0, stream>>>(
        (const float4*)bufP, (const float4*)bufD, eps1, (float4*)bufD, N * 128 / 4);

    // ---------------- layer 2: h1 -> h2 in bufD ----------------
    gemm_rows<128><<<blocks(N), TPB, 0, stream>>>(bufD, W2, bufP, N);
    hipMemsetAsync(bufC, 0, (size_t)E * 128 * 4, stream);
    scatter_ve<128><<<blocks((long long)nnz * 32), TPB, 0, stream>>>(bufP, vertex, edges, bufC, nnz);
    hipMemsetAsync(bufD, 0, (size_t)N * 128 * 4, stream);   // h1 dead after gemm
    scatter_ev<128><<<blocks((long long)nnz * 32), TPB, 0, stream>>>(bufC, inv, vertex, edges, bufD, nnz);
    combine4<true><<<blocks((long long)N * 128 / 4), TPB, 0, stream>>>(
        (const float4*)bufP, (const float4*)bufD, eps2, (float4*)bufD, N * 128 / 4);

    // ---------------- layer 3: h2 -> (out, Xe), NO = 64 ----------------
    gemm_rows<64><<<blocks(N), TPB, 0, stream>>>(bufD, W3, bufP, N);
    hipMemsetAsync(bufC, 0, (size_t)E * 64 * 4, stream);
    scatter_ve<64><<<blocks((long long)nnz * 16), TPB, 0, stream>>>(bufP, vertex, edges, bufC, nnz);
    hipMemsetAsync(bufD, 0, (size_t)N * 64 * 4, stream);    // h2 dead after gemm
    scatter_ev<64><<<blocks((long long)nnz * 16), TPB, 0, stream>>>(bufC, inv, vertex, edges, bufD, nnz);
    combine4<false><<<blocks((long long)N * 64 / 4), TPB, 0, stream>>>(
        (const float4*)bufP, (const float4*)bufD, eps3, (float4*)outV, N * 64 / 4);
    xeout_kernel<<<blocks((long long)E * 64), TPB, 0, stream>>>(bufC, inv, outE, E * 64);
}

// Round 3
// 1351.061 us; speedup vs baseline: 5.2394x; 5.2394x over previous
//
#include <hip/hip_runtime.h>

static constexpr int KDIM   = 128;   // input feature dim of every layer
static constexpr int NEDGES = 20000;

// ---------------- GEMM: P[N,NO] = H[N,128] @ W[128,NO] ----------------
// One thread per output row; W staged in LDS, wave-uniform broadcast reads.
// IN-PLACE SAFE: the full input row is staged into registers BEFORE any
// write to P (H and P may alias, e.g. layer-2 h->P in the same buffer).
template<int NO>
__global__ __launch_bounds__(256) void gemm_rows(const float* H,
                                                 const float* __restrict__ W,
                                                 float* P, int N) {
    __shared__ float Wl[KDIM * NO];
    for (int i = threadIdx.x; i < KDIM * NO; i += 256) Wl[i] = W[i];
    __syncthreads();
    int row = blockIdx.x * 256 + threadIdx.x;
    if (row >= N) return;

    // stage the whole row in registers (32 x float4 = 128 VGPR)
    float4 xr[KDIM / 4];
    const float4* src = reinterpret_cast<const float4*>(H + (size_t)row * KDIM);
#pragma unroll
    for (int i = 0; i < KDIM / 4; ++i) xr[i] = src[i];

    float* pr = P + (size_t)row * NO;
#pragma unroll
    for (int cb = 0; cb < NO / 32; ++cb) {
        float acc[32];
#pragma unroll
        for (int j = 0; j < 32; ++j) acc[j] = 0.0f;
#pragma unroll
        for (int k4 = 0; k4 < KDIM / 4; ++k4) {
            const float xs[4] = {xr[k4].x, xr[k4].y, xr[k4].z, xr[k4].w};
#pragma unroll
            for (int kk = 0; kk < 4; ++kk) {
                const float* wrow = &Wl[(k4 * 4 + kk) * NO + cb * 32];
#pragma unroll
                for (int j = 0; j < 32; ++j) acc[j] = fmaf(xs[kk], wrow[j], acc[j]);
            }
        }
#pragma unroll
        for (int j = 0; j < 32; j += 4) {
            float4 o;
            o.x = acc[j]; o.y = acc[j + 1]; o.z = acc[j + 2]; o.w = acc[j + 3];
            *reinterpret_cast<float4*>(pr + cb * 32 + j) = o;
        }
    }
}

// ---------------- CSR build: histogram, scan, fill ----------------
__global__ __launch_bounds__(256) void hist_kernel(const int* __restrict__ vertex,
                                                   const int* __restrict__ edges,
                                                   int* __restrict__ ecnt,
                                                   int* __restrict__ vcnt, int nnz) {
    int i = blockIdx.x * 256 + threadIdx.x;
    if (i >= nnz) return;
    atomicAdd(&ecnt[edges[i]], 1);
    atomicAdd(&vcnt[vertex[i]], 1);
}

// Single-block exclusive scan: off[0..n] (off[n]=total), cur = copy of off[0..n-1].
__global__ __launch_bounds__(1024) void scan_kernel(const int* __restrict__ cnt,
                                                    int* __restrict__ off,
                                                    int* __restrict__ cur, int n) {
    __shared__ int sh[1024];
    const int t = threadIdx.x;
    const int c = (n + 1023) >> 10;
    const int lo = t * c;
    const int hi = min(n, lo + c);
    int s = 0;
    for (int i = lo; i < hi; ++i) s += cnt[i];
    sh[t] = s;
    __syncthreads();
    for (int d = 1; d < 1024; d <<= 1) {
        int val = (t >= d) ? sh[t - d] : 0;
        __syncthreads();
        sh[t] += val;
        __syncthreads();
    }
    int base = (t == 0) ? 0 : sh[t - 1];   // exclusive prefix of this chunk
    for (int i = lo; i < hi; ++i) {
        off[i] = base;
        cur[i] = base;
        base += cnt[i];
    }
    if (t == 1023) off[n] = sh[1023];
}

__global__ __launch_bounds__(256) void fill_kernel(const int* __restrict__ vertex,
                                                   const int* __restrict__ edges,
                                                   int* __restrict__ ecur,
                                                   int* __restrict__ vcur,
                                                   int* __restrict__ ebucket,
                                                   int* __restrict__ vbucket, int nnz) {
    int i = blockIdx.x * 256 + threadIdx.x;
    if (i >= nnz) return;
    int e = edges[i], v = vertex[i];
    ebucket[atomicAdd(&ecur[e], 1)] = v;   // entries grouped by edge, store vertex id
    vbucket[atomicAdd(&vcur[v], 1)] = e;   // entries grouped by vertex, store edge id
}

__global__ __launch_bounds__(256) void inv_kernel(const int* __restrict__ ecnt,
                                                  float* __restrict__ inv, int E) {
    int i = blockIdx.x * 256 + threadIdx.x;
    if (i < E) inv[i] = 1.0f / fmaxf((float)ecnt[i], 1.0f);
}

// ---------------- edge gather: Xe[e] = mean over entries of P[vertex] ----------------
// One wave per edge; lane covers NO/64 floats.
template<int NO>
__global__ __launch_bounds__(256) void edge_gather(const float* __restrict__ P,
                                                   const int* __restrict__ ebucket,
                                                   const int* __restrict__ eoff,
                                                   const float* __restrict__ inv,
                                                   float* __restrict__ Xe, int E) {
    int wid = (blockIdx.x * 256 + threadIdx.x) >> 6;
    if (wid >= E) return;
    const int lane = threadIdx.x & 63;
    constexpr int FPL = NO / 64;
    const int j1 = eoff[wid + 1];
    int j = eoff[wid];
    float acc0 = 0.0f, acc1 = 0.0f;
    for (; j + 2 <= j1; j += 2) {                 // 2x unroll: 2 independent row loads
        int v0 = ebucket[j], v1 = ebucket[j + 1];
        if constexpr (FPL == 2) {
            float2 a = *reinterpret_cast<const float2*>(P + (size_t)v0 * NO + lane * 2);
            float2 b = *reinterpret_cast<const float2*>(P + (size_t)v1 * NO + lane * 2);
            acc0 += a.x + b.x;
            acc1 += a.y + b.y;
        } else {
            acc0 += P[(size_t)v0 * NO + lane] + P[(size_t)v1 * NO + lane];
        }
    }
    if (j < j1) {
        int v0 = ebucket[j];
        if constexpr (FPL == 2) {
            float2 a = *reinterpret_cast<const float2*>(P + (size_t)v0 * NO + lane * 2);
            acc0 += a.x; acc1 += a.y;
        } else {
            acc0 += P[(size_t)v0 * NO + lane];
        }
    }
    const float s = inv[wid];
    if constexpr (FPL == 2) {
        float2 o; o.x = acc0 * s; o.y = acc1 * s;
        *reinterpret_cast<float2*>(Xe + (size_t)wid * NO + lane * 2) = o;
    } else {
        Xe[(size_t)wid * NO + lane] = acc0 * s;
    }
}

// ---------------- vertex gather + combine: out[v] = relu?((1+eps)*P[v] + sum Xe[e]) ----------------
// One wave per vertex. P and out may alias (row-local): the wave reads only
// its own P row (once, at the end) and writes only its own out row.
template<int NO, bool RELU>
__global__ __launch_bounds__(256) void vertex_gather(const float* P,
                                                     const float* __restrict__ Xe,
                                                     const int* __restrict__ vbucket,
                                                     const int* __restrict__ voff,
                                                     const float* __restrict__ eps,
                                                     float* out, int N) {
    int wid = (blockIdx.x * 256 + threadIdx.x) >> 6;
    if (wid >= N) return;
    const int lane = threadIdx.x & 63;
    constexpr int FPL = NO / 64;
    const int j1 = voff[wid + 1];
    int j = voff[wid];
    float acc0 = 0.0f, acc1 = 0.0f;
    for (; j + 2 <= j1; j += 2) {
        int e0 = vbucket[j], e1 = vbucket[j + 1];
        if constexpr (FPL == 2) {
            float2 a = *reinterpret_cast<const float2*>(Xe + (size_t)e0 * NO + lane * 2);
            float2 b = *reinterpret_cast<const float2*>(Xe + (size_t)e1 * NO + lane * 2);
            acc0 += a.x + b.x;
            acc1 += a.y + b.y;
        } else {
            acc0 += Xe[(size_t)e0 * NO + lane] + Xe[(size_t)e1 * NO + lane];
        }
    }
    if (j < j1) {
        int e0 = vbucket[j];
        if constexpr (FPL == 2) {
            float2 a = *reinterpret_cast<const float2*>(Xe + (size_t)e0 * NO + lane * 2);
            acc0 += a.x; acc1 += a.y;
        } else {
            acc0 += Xe[(size_t)e0 * NO + lane];
        }
    }
    const float g = 1.0f + eps[0];
    if constexpr (FPL == 2) {
        float2 p = *reinterpret_cast<const float2*>(P + (size_t)wid * NO + lane * 2);
        float2 o;
        o.x = fmaf(g, p.x, acc0);
        o.y = fmaf(g, p.y, acc1);
        if (RELU) { o.x = fmaxf(o.x, 0.0f); o.y = fmaxf(o.y, 0.0f); }
        *reinterpret_cast<float2*>(out + (size_t)wid * NO + lane * 2) = o;
    } else {
        float p = P[(size_t)wid * NO + lane];
        float o = fmaf(g, p, acc0);
        if (RELU) o = fmaxf(o, 0.0f);
        out[(size_t)wid * NO + lane] = o;
    }
}

extern "C" void kernel_launch(void* const* d_in, const int* in_sizes, int n_in,
                              void* d_out, int out_size, void* d_ws, size_t ws_size,
                              hipStream_t stream) {
    const float* X      = (const float*)d_in[0];
    const int*   vertex = (const int*)d_in[1];
    const int*   edges  = (const int*)d_in[2];
    const float* W1     = (const float*)d_in[3];
    const float* W2     = (const float*)d_in[4];
    const float* W3     = (const float*)d_in[5];
    const float* eps1   = (const float*)d_in[6];
    const float* eps2   = (const float*)d_in[7];
    const float* eps3   = (const float*)d_in[8];

    const int N   = in_sizes[0] / KDIM;   // 100000
    const int nnz = in_sizes[1];          // 800000
    const int E   = NEDGES;               // 20000

    // ---------------- workspace carve-up (~94 MB) ----------------
    char* ws = (char*)d_ws;
    size_t off = 0;
    auto carve = [&](size_t bytes) { void* p = ws + off; off += (bytes + 255) & ~(size_t)255; return p; };
    float* bufA    = (float*)carve((size_t)N * 128 * 4);   // node buffer (h/P in-place)
    float* bufP3   = (float*)carve((size_t)N * 64 * 4);    // layer-3 projection
    float* XeBuf   = (float*)carve((size_t)E * 128 * 4);   // edge features (layers 1,2)
    float* inv     = (float*)carve((size_t)E * 4);
    int*   ecnt    = (int*)carve((size_t)E * 4);
    int*   eoff    = (int*)carve((size_t)(E + 1) * 4);
    int*   ecur    = (int*)carve((size_t)E * 4);
    int*   vcnt    = (int*)carve((size_t)N * 4);
    int*   voff    = (int*)carve((size_t)(N + 1) * 4);
    int*   vcur    = (int*)carve((size_t)N * 4);
    int*   ebucket = (int*)carve((size_t)nnz * 4);
    int*   vbucket = (int*)carve((size_t)nnz * 4);

    float* outV = (float*)d_out;                 // N*64
    float* outE = outV + (size_t)N * 64;         // E*64 (layer-3 Xe, written directly)

    const int TPB = 256;
    auto blocks = [](long long t) { return (unsigned)((t + 255) / 256); };

    // ---------------- CSR build (once per call, reused by all 3 layers) ----------------
    hipMemsetAsync(ecnt, 0, (size_t)E * 4, stream);
    hipMemsetAsync(vcnt, 0, (size_t)N * 4, stream);
    hist_kernel<<<blocks(nnz), TPB, 0, stream>>>(vertex, edges, ecnt, vcnt, nnz);
    scan_kernel<<<1, 1024, 0, stream>>>(ecnt, eoff, ecur, E);
    scan_kernel<<<1, 1024, 0, stream>>>(vcnt, voff, vcur, N);
    inv_kernel<<<blocks(E), TPB, 0, stream>>>(ecnt, inv, E);
    fill_kernel<<<blocks(nnz), TPB, 0, stream>>>(vertex, edges, ecur, vcur, ebucket, vbucket, nnz);

    // ---------------- layer 1: X -> h1 (in bufA) ----------------
    gemm_rows<128><<<blocks(N), TPB, 0, stream>>>(X, W1, bufA, N);
    edge_gather<128><<<blocks((long long)E * 64), TPB, 0, stream>>>(bufA, ebucket, eoff, inv, XeBuf, E);
    vertex_gather<128, true><<<blocks((long long)N * 64), TPB, 0, stream>>>(bufA, XeBuf, vbucket, voff, eps1, bufA, N);

    // ---------------- layer 2: h1 -> h2 (in bufA, register-staged in-place GEMM) ----------------
    gemm_rows<128><<<blocks(N), TPB, 0, stream>>>(bufA, W2, bufA, N);
    edge_gather<128><<<blocks((long long)E * 64), TPB, 0, stream>>>(bufA, ebucket, eoff, inv, XeBuf, E);
    vertex_gather<128, true><<<blocks((long long)N * 64), TPB, 0, stream>>>(bufA, XeBuf, vbucket, voff, eps2, bufA, N);

    // ---------------- layer 3: h2 -> (outV, outE), NO = 64 ----------------
    gemm_rows<64><<<blocks(N), TPB, 0, stream>>>(bufA, W3, bufP3, N);
    edge_gather<64><<<blocks((long long)E * 64), TPB, 0, stream>>>(bufP3, ebucket, eoff, inv, outE, E);
    vertex_gather<64, false><<<blocks((long long)N * 64), TPB, 0, stream>>>(bufP3, outE, vbucket, voff, eps3, outV, N);
}

// Round 4
// 1117.528 us; speedup vs baseline: 6.3343x; 1.2090x over previous
//
#include <hip/hip_runtime.h>

static constexpr int KDIM   = 128;   // input feature dim of every layer
static constexpr int NEDGES = 20000;
static constexpr int SCAN_CHUNK = 2048;   // elements per block in hierarchical scan

// ---------------- GEMM: P[N,NO] = H[N,128] @ W[128,NO] ----------------
// One thread per output row; W staged in LDS, wave-uniform broadcast reads.
// IN-PLACE SAFE: the full input row is staged into registers BEFORE any
// write to P (H and P may alias, e.g. layer-2 h->P in the same buffer).
template<int NO>
__global__ __launch_bounds__(256) void gemm_rows(const float* H,
                                                 const float* __restrict__ W,
                                                 float* P, int N) {
    __shared__ float Wl[KDIM * NO];
    for (int i = threadIdx.x; i < KDIM * NO; i += 256) Wl[i] = W[i];
    __syncthreads();
    int row = blockIdx.x * 256 + threadIdx.x;
    if (row >= N) return;

    // stage the whole row in registers (32 x float4 = 128 VGPR)
    float4 xr[KDIM / 4];
    const float4* src = reinterpret_cast<const float4*>(H + (size_t)row * KDIM);
#pragma unroll
    for (int i = 0; i < KDIM / 4; ++i) xr[i] = src[i];

    float* pr = P + (size_t)row * NO;
#pragma unroll
    for (int cb = 0; cb < NO / 32; ++cb) {
        float acc[32];
#pragma unroll
        for (int j = 0; j < 32; ++j) acc[j] = 0.0f;
#pragma unroll
        for (int k4 = 0; k4 < KDIM / 4; ++k4) {
            const float xs[4] = {xr[k4].x, xr[k4].y, xr[k4].z, xr[k4].w};
#pragma unroll
            for (int kk = 0; kk < 4; ++kk) {
                const float* wrow = &Wl[(k4 * 4 + kk) * NO + cb * 32];
#pragma unroll
                for (int j = 0; j < 32; ++j) acc[j] = fmaf(xs[kk], wrow[j], acc[j]);
            }
        }
#pragma unroll
        for (int j = 0; j < 32; j += 4) {
            float4 o;
            o.x = acc[j]; o.y = acc[j + 1]; o.z = acc[j + 2]; o.w = acc[j + 3];
            *reinterpret_cast<float4*>(pr + cb * 32 + j) = o;
        }
    }
}

// ---------------- CSR build: histogram, hierarchical scan, fill ----------------
__global__ __launch_bounds__(256) void hist_kernel(const int* __restrict__ vertex,
                                                   const int* __restrict__ edges,
                                                   int* __restrict__ ecnt,
                                                   int* __restrict__ vcnt, int nnz) {
    int i = blockIdx.x * 256 + threadIdx.x;
    if (i >= nnz) return;
    atomicAdd(&ecnt[edges[i]], 1);
    atomicAdd(&vcnt[vertex[i]], 1);
}

// phase A: per-block sums over SCAN_CHUNK elements (coalesced, stride-256)
__global__ __launch_bounds__(256) void scan_blocksum(const int* __restrict__ cnt,
                                                     int* __restrict__ bsum, int n) {
    __shared__ int sh[256];
    const int base = blockIdx.x * SCAN_CHUNK;
    int s = 0;
#pragma unroll
    for (int k = 0; k < SCAN_CHUNK / 256; ++k) {
        int idx = base + k * 256 + threadIdx.x;
        if (idx < n) s += cnt[idx];
    }
    sh[threadIdx.x] = s;
    __syncthreads();
    for (int d = 128; d > 0; d >>= 1) {
        if (threadIdx.x < d) sh[threadIdx.x] += sh[threadIdx.x + d];
        __syncthreads();
    }
    if (threadIdx.x == 0) bsum[blockIdx.x] = sh[0];
}

// phase B: exclusive scan of block sums (nb <= 1024), one small block
__global__ __launch_bounds__(1024) void scan_bsum(int* __restrict__ bsum, int nb) {
    __shared__ int sh[1024];
    const int t = threadIdx.x;
    sh[t] = (t < nb) ? bsum[t] : 0;
    __syncthreads();
    for (int d = 1; d < 1024; d <<= 1) {
        int v = (t >= d) ? sh[t - d] : 0;
        __syncthreads();
        sh[t] += v;
        __syncthreads();
    }
    if (t < nb) bsum[t] = (t == 0) ? 0 : sh[t - 1];
}

// phase C: local scan + block base -> off/cur (+ inv for the edge variant)
template<bool WITH_INV>
__global__ __launch_bounds__(256) void scan_final(const int* __restrict__ cnt,
                                                  const int* __restrict__ bsum,
                                                  int* __restrict__ off,
                                                  int* __restrict__ cur,
                                                  float* __restrict__ inv, int n) {
    __shared__ int sh[256];
    const int t = threadIdx.x;
    const int base = blockIdx.x * SCAN_CHUNK;
    constexpr int EPT = SCAN_CHUNK / 256;   // 8
    int loc[EPT];
    int s = 0;
#pragma unroll
    for (int k = 0; k < EPT; ++k) {
        int idx = base + t * EPT + k;
        loc[k] = (idx < n) ? cnt[idx] : 0;
        s += loc[k];
    }
    sh[t] = s;
    __syncthreads();
    for (int d = 1; d < 256; d <<= 1) {
        int v = (t >= d) ? sh[t - d] : 0;
        __syncthreads();
        sh[t] += v;
        __syncthreads();
    }
    int run = bsum[blockIdx.x] + ((t == 0) ? 0 : sh[t - 1]);
#pragma unroll
    for (int k = 0; k < EPT; ++k) {
        int idx = base + t * EPT + k;
        if (idx < n) {
            off[idx] = run;
            cur[idx] = run;
            if (WITH_INV) inv[idx] = 1.0f / fmaxf((float)loc[k], 1.0f);
            run += loc[k];
            if (idx == n - 1) off[n] = run;
        }
    }
}

__global__ __launch_bounds__(256) void fill_kernel(const int* __restrict__ vertex,
                                                   const int* __restrict__ edges,
                                                   int* __restrict__ ecur,
                                                   int* __restrict__ vcur,
                                                   int* __restrict__ ebucket,
                                                   int* __restrict__ vbucket, int nnz) {
    int i = blockIdx.x * 256 + threadIdx.x;
    if (i >= nnz) return;
    int e = edges[i], v = vertex[i];
    ebucket[atomicAdd(&ecur[e], 1)] = v;   // entries grouped by edge, store vertex id
    vbucket[atomicAdd(&vcur[v], 1)] = e;   // entries grouped by vertex, store edge id
}

// ---------------- edge gather: Xe[e] = mean over entries of P[vertex] ----------------
// One wave per edge; lane covers NO/64 floats.
template<int NO>
__global__ __launch_bounds__(256) void edge_gather(const float* __restrict__ P,
                                                   const int* __restrict__ ebucket,
                                                   const int* __restrict__ eoff,
                                                   const float* __restrict__ inv,
                                                   float* __restrict__ Xe, int E) {
    int wid = (blockIdx.x * 256 + threadIdx.x) >> 6;
    if (wid >= E) return;
    const int lane = threadIdx.x & 63;
    constexpr int FPL = NO / 64;
    const int j1 = eoff[wid + 1];
    int j = eoff[wid];
    float acc0 = 0.0f, acc1 = 0.0f;
    for (; j + 2 <= j1; j += 2) {                 // 2x unroll: 2 independent row loads
        int v0 = ebucket[j], v1 = ebucket[j + 1];
        if constexpr (FPL == 2) {
            float2 a = *reinterpret_cast<const float2*>(P + (size_t)v0 * NO + lane * 2);
            float2 b = *reinterpret_cast<const float2*>(P + (size_t)v1 * NO + lane * 2);
            acc0 += a.x + b.x;
            acc1 += a.y + b.y;
        } else {
            acc0 += P[(size_t)v0 * NO + lane] + P[(size_t)v1 * NO + lane];
        }
    }
    if (j < j1) {
        int v0 = ebucket[j];
        if constexpr (FPL == 2) {
            float2 a = *reinterpret_cast<const float2*>(P + (size_t)v0 * NO + lane * 2);
            acc0 += a.x; acc1 += a.y;
        } else {
            acc0 += P[(size_t)v0 * NO + lane];
        }
    }
    const float s = inv[wid];
    if constexpr (FPL == 2) {
        float2 o; o.x = acc0 * s; o.y = acc1 * s;
        *reinterpret_cast<float2*>(Xe + (size_t)wid * NO + lane * 2) = o;
    } else {
        Xe[(size_t)wid * NO + lane] = acc0 * s;
    }
}

// ---------------- vertex gather + combine: out[v] = relu?((1+eps)*P[v] + sum Xe[e]) ----------------
// One wave per vertex. P and out may alias (row-local): the wave reads only
// its own P row (once, at the end) and writes only its own out row.
template<int NO, bool RELU>
__global__ __launch_bounds__(256) void vertex_gather(const float* P,
                                                     const float* __restrict__ Xe,
                                                     const int* __restrict__ vbucket,
                                                     const int* __restrict__ voff,
                                                     const float* __restrict__ eps,
                                                     float* out, int N) {
    int wid = (blockIdx.x * 256 + threadIdx.x) >> 6;
    if (wid >= N) return;
    const int lane = threadIdx.x & 63;
    constexpr int FPL = NO / 64;
    const int j1 = voff[wid + 1];
    int j = voff[wid];
    float acc0 = 0.0f, acc1 = 0.0f;
    for (; j + 2 <= j1; j += 2) {
        int e0 = vbucket[j], e1 = vbucket[j + 1];
        if constexpr (FPL == 2) {
            float2 a = *reinterpret_cast<const float2*>(Xe + (size_t)e0 * NO + lane * 2);
            float2 b = *reinterpret_cast<const float2*>(Xe + (size_t)e1 * NO + lane * 2);
            acc0 += a.x + b.x;
            acc1 += a.y + b.y;
        } else {
            acc0 += Xe[(size_t)e0 * NO + lane] + Xe[(size_t)e1 * NO + lane];
        }
    }
    if (j < j1) {
        int e0 = vbucket[j];
        if constexpr (FPL == 2) {
            float2 a = *reinterpret_cast<const float2*>(Xe + (size_t)e0 * NO + lane * 2);
            acc0 += a.x; acc1 += a.y;
        } else {
            acc0 += Xe[(size_t)e0 * NO + lane];
        }
    }
    const float g = 1.0f + eps[0];
    if constexpr (FPL == 2) {
        float2 p = *reinterpret_cast<const float2*>(P + (size_t)wid * NO + lane * 2);
        float2 o;
        o.x = fmaf(g, p.x, acc0);
        o.y = fmaf(g, p.y, acc1);
        if (RELU) { o.x = fmaxf(o.x, 0.0f); o.y = fmaxf(o.y, 0.0f); }
        *reinterpret_cast<float2*>(out + (size_t)wid * NO + lane * 2) = o;
    } else {
        float p = P[(size_t)wid * NO + lane];
        float o = fmaf(g, p, acc0);
        if (RELU) o = fmaxf(o, 0.0f);
        out[(size_t)wid * NO + lane] = o;
    }
}

extern "C" void kernel_launch(void* const* d_in, const int* in_sizes, int n_in,
                              void* d_out, int out_size, void* d_ws, size_t ws_size,
                              hipStream_t stream) {
    const float* X      = (const float*)d_in[0];
    const int*   vertex = (const int*)d_in[1];
    const int*   edges  = (const int*)d_in[2];
    const float* W1     = (const float*)d_in[3];
    const float* W2     = (const float*)d_in[4];
    const float* W3     = (const float*)d_in[5];
    const float* eps1   = (const float*)d_in[6];
    const float* eps2   = (const float*)d_in[7];
    const float* eps3   = (const float*)d_in[8];

    const int N   = in_sizes[0] / KDIM;   // 100000
    const int nnz = in_sizes[1];          // 800000
    const int E   = NEDGES;               // 20000

    // ---------------- workspace carve-up (~94 MB) ----------------
    char* ws = (char*)d_ws;
    size_t off = 0;
    auto carve = [&](size_t bytes) { void* p = ws + off; off += (bytes + 255) & ~(size_t)255; return p; };
    float* bufA    = (float*)carve((size_t)N * 128 * 4);   // node buffer (h/P in-place)
    float* bufP3   = (float*)carve((size_t)N * 64 * 4);    // layer-3 projection
    float* XeBuf   = (float*)carve((size_t)E * 128 * 4);   // edge features (layers 1,2)
    float* inv     = (float*)carve((size_t)E * 4);
    int*   ecnt    = (int*)carve((size_t)E * 4);
    int*   eoff    = (int*)carve((size_t)(E + 1) * 4);
    int*   ecur    = (int*)carve((size_t)E * 4);
    int*   vcnt    = (int*)carve((size_t)N * 4);
    int*   voff    = (int*)carve((size_t)(N + 1) * 4);
    int*   vcur    = (int*)carve((size_t)N * 4);
    int*   ebucket = (int*)carve((size_t)nnz * 4);
    int*   vbucket = (int*)carve((size_t)nnz * 4);
    int*   bsumE   = (int*)carve((size_t)1024 * 4);
    int*   bsumV   = (int*)carve((size_t)1024 * 4);

    float* outV = (float*)d_out;                 // N*64
    float* outE = outV + (size_t)N * 64;         // E*64 (layer-3 Xe, written directly)

    const int TPB = 256;
    auto blocks = [](long long t) { return (unsigned)((t + 255) / 256); };
    const int nbE = (E + SCAN_CHUNK - 1) / SCAN_CHUNK;   // 10
    const int nbV = (N + SCAN_CHUNK - 1) / SCAN_CHUNK;   // 49

    // ---------------- CSR build (once per call, reused by all 3 layers) ----------------
    hipMemsetAsync(ecnt, 0, (size_t)E * 4, stream);
    hipMemsetAsync(vcnt, 0, (size_t)N * 4, stream);
    hist_kernel<<<blocks(nnz), TPB, 0, stream>>>(vertex, edges, ecnt, vcnt, nnz);
    scan_blocksum<<<nbE, TPB, 0, stream>>>(ecnt, bsumE, E);
    scan_blocksum<<<nbV, TPB, 0, stream>>>(vcnt, bsumV, N);
    scan_bsum<<<1, 1024, 0, stream>>>(bsumE, nbE);
    scan_bsum<<<1, 1024, 0, stream>>>(bsumV, nbV);
    scan_final<true><<<nbE, TPB, 0, stream>>>(ecnt, bsumE, eoff, ecur, inv, E);
    scan_final<false><<<nbV, TPB, 0, stream>>>(vcnt, bsumV, voff, vcur, nullptr, N);
    fill_kernel<<<blocks(nnz), TPB, 0, stream>>>(vertex, edges, ecur, vcur, ebucket, vbucket, nnz);

    // ---------------- layer 1: X -> h1 (in bufA) ----------------
    gemm_rows<128><<<blocks(N), TPB, 0, stream>>>(X, W1, bufA, N);
    edge_gather<128><<<blocks((long long)E * 64), TPB, 0, stream>>>(bufA, ebucket, eoff, inv, XeBuf, E);
    vertex_gather<128, true><<<blocks((long long)N * 64), TPB, 0, stream>>>(bufA, XeBuf, vbucket, voff, eps1, bufA, N);

    // ---------------- layer 2: h1 -> h2 (in bufA, register-staged in-place GEMM) ----------------
    gemm_rows<128><<<blocks(N), TPB, 0, stream>>>(bufA, W2, bufA, N);
    edge_gather<128><<<blocks((long long)E * 64), TPB, 0, stream>>>(bufA, ebucket, eoff, inv, XeBuf, E);
    vertex_gather<128, true><<<blocks((long long)N * 64), TPB, 0, stream>>>(bufA, XeBuf, vbucket, voff, eps2, bufA, N);

    // ---------------- layer 3: h2 -> (outV, outE), NO = 64 ----------------
    gemm_rows<64><<<blocks(N), TPB, 0, stream>>>(bufA, W3, bufP3, N);
    edge_gather<64><<<blocks((long long)E * 64), TPB, 0, stream>>>(bufP3, ebucket, eoff, inv, outE, E);
    vertex_gather<64, false><<<blocks((long long)N * 64), TPB, 0, stream>>>(bufP3, outE, vbucket, voff, eps3, outV, N);
}

// Round 5
// 866.051 us; speedup vs baseline: 8.1736x; 1.2904x over previous
//
#include <hip/hip_runtime.h>

static constexpr int KDIM   = 128;   // input feature dim of every layer
static constexpr int NEDGES = 20000;
static constexpr int SCAN_CHUNK = 2048;   // elements per block in hierarchical scan

// ---------------- tiled GEMM: P[N,NO] = H[N,128] @ W[128,NO] ----------------
// grid = (row-blocks, NO/32). Block stages a 128x32 W column-panel in LDS
// (16 KB), each thread streams its row and computes 32 outputs. H != P.
template<int NO>
__global__ __launch_bounds__(256) void gemm_tile(const float* __restrict__ H,
                                                 const float* __restrict__ W,
                                                 float* __restrict__ P, int N) {
    constexpr int CB = 32;
    __shared__ float Wl[KDIM * CB];
    const int cb0 = blockIdx.y * CB;
    for (int i = threadIdx.x; i < KDIM * CB; i += 256) {
        int k = i >> 5, j = i & 31;
        Wl[i] = W[k * NO + cb0 + j];
    }
    __syncthreads();
    int row = blockIdx.x * 256 + threadIdx.x;
    if (row >= N) return;
    const float4* xr = reinterpret_cast<const float4*>(H + (size_t)row * KDIM);
    float acc[CB];
#pragma unroll
    for (int j = 0; j < CB; ++j) acc[j] = 0.0f;
#pragma unroll
    for (int k4 = 0; k4 < KDIM / 4; ++k4) {
        const float4 xv = xr[k4];
        const float xs[4] = {xv.x, xv.y, xv.z, xv.w};
#pragma unroll
        for (int kk = 0; kk < 4; ++kk) {
            const float* wrow = &Wl[(k4 * 4 + kk) * CB];
#pragma unroll
            for (int j = 0; j < CB; ++j) acc[j] = fmaf(xs[kk], wrow[j], acc[j]);
        }
    }
    float* pr = P + (size_t)row * NO + cb0;
#pragma unroll
    for (int j = 0; j < CB; j += 4) {
        float4 o;
        o.x = acc[j]; o.y = acc[j + 1]; o.z = acc[j + 2]; o.w = acc[j + 3];
        *reinterpret_cast<float4*>(pr + j) = o;
    }
}

// ---------------- fallback GEMM (in-place safe): register-staged row ----------------
template<int NO>
__global__ __launch_bounds__(256) void gemm_rows(const float* H,
                                                 const float* __restrict__ W,
                                                 float* P, int N) {
    __shared__ float Wl[KDIM * NO];
    for (int i = threadIdx.x; i < KDIM * NO; i += 256) Wl[i] = W[i];
    __syncthreads();
    int row = blockIdx.x * 256 + threadIdx.x;
    if (row >= N) return;
    float4 xr[KDIM / 4];
    const float4* src = reinterpret_cast<const float4*>(H + (size_t)row * KDIM);
#pragma unroll
    for (int i = 0; i < KDIM / 4; ++i) xr[i] = src[i];
    float* pr = P + (size_t)row * NO;
#pragma unroll
    for (int cb = 0; cb < NO / 32; ++cb) {
        float acc[32];
#pragma unroll
        for (int j = 0; j < 32; ++j) acc[j] = 0.0f;
#pragma unroll
        for (int k4 = 0; k4 < KDIM / 4; ++k4) {
            const float xs[4] = {xr[k4].x, xr[k4].y, xr[k4].z, xr[k4].w};
#pragma unroll
            for (int kk = 0; kk < 4; ++kk) {
                const float* wrow = &Wl[(k4 * 4 + kk) * NO + cb * 32];
#pragma unroll
                for (int j = 0; j < 32; ++j) acc[j] = fmaf(xs[kk], wrow[j], acc[j]);
            }
        }
#pragma unroll
        for (int j = 0; j < 32; j += 4) {
            float4 o;
            o.x = acc[j]; o.y = acc[j + 1]; o.z = acc[j + 2]; o.w = acc[j + 3];
            *reinterpret_cast<float4*>(pr + cb * 32 + j) = o;
        }
    }
}

// ---------------- CSR build: histogram, hierarchical scan, fill ----------------
__global__ __launch_bounds__(256) void hist_kernel(const int* __restrict__ vertex,
                                                   const int* __restrict__ edges,
                                                   int* __restrict__ ecnt,
                                                   int* __restrict__ vcnt, int nnz) {
    int i = blockIdx.x * 256 + threadIdx.x;
    if (i >= nnz) return;
    atomicAdd(&ecnt[edges[i]], 1);
    atomicAdd(&vcnt[vertex[i]], 1);
}

__global__ __launch_bounds__(256) void scan_blocksum(const int* __restrict__ cnt,
                                                     int* __restrict__ bsum, int n) {
    __shared__ int sh[256];
    const int base = blockIdx.x * SCAN_CHUNK;
    int s = 0;
#pragma unroll
    for (int k = 0; k < SCAN_CHUNK / 256; ++k) {
        int idx = base + k * 256 + threadIdx.x;
        if (idx < n) s += cnt[idx];
    }
    sh[threadIdx.x] = s;
    __syncthreads();
    for (int d = 128; d > 0; d >>= 1) {
        if (threadIdx.x < d) sh[threadIdx.x] += sh[threadIdx.x + d];
        __syncthreads();
    }
    if (threadIdx.x == 0) bsum[blockIdx.x] = sh[0];
}

__global__ __launch_bounds__(1024) void scan_bsum(int* __restrict__ bsum, int nb) {
    __shared__ int sh[1024];
    const int t = threadIdx.x;
    sh[t] = (t < nb) ? bsum[t] : 0;
    __syncthreads();
    for (int d = 1; d < 1024; d <<= 1) {
        int v = (t >= d) ? sh[t - d] : 0;
        __syncthreads();
        sh[t] += v;
        __syncthreads();
    }
    if (t < nb) bsum[t] = (t == 0) ? 0 : sh[t - 1];
}

template<bool WITH_INV>
__global__ __launch_bounds__(256) void scan_final(const int* __restrict__ cnt,
                                                  const int* __restrict__ bsum,
                                                  int* __restrict__ off,
                                                  int* __restrict__ cur,
                                                  float* __restrict__ inv, int n) {
    __shared__ int sh[256];
    const int t = threadIdx.x;
    const int base = blockIdx.x * SCAN_CHUNK;
    constexpr int EPT = SCAN_CHUNK / 256;   // 8
    int loc[EPT];
    int s = 0;
#pragma unroll
    for (int k = 0; k < EPT; ++k) {
        int idx = base + t * EPT + k;
        loc[k] = (idx < n) ? cnt[idx] : 0;
        s += loc[k];
    }
    sh[t] = s;
    __syncthreads();
    for (int d = 1; d < 256; d <<= 1) {
        int v = (t >= d) ? sh[t - d] : 0;
        __syncthreads();
        sh[t] += v;
        __syncthreads();
    }
    int run = bsum[blockIdx.x] + ((t == 0) ? 0 : sh[t - 1]);
#pragma unroll
    for (int k = 0; k < EPT; ++k) {
        int idx = base + t * EPT + k;
        if (idx < n) {
            off[idx] = run;
            cur[idx] = run;
            if (WITH_INV) inv[idx] = 1.0f / fmaxf((float)loc[k], 1.0f);
            run += loc[k];
            if (idx == n - 1) off[n] = run;
        }
    }
}

__global__ __launch_bounds__(256) void fill_kernel(const int* __restrict__ vertex,
                                                   const int* __restrict__ edges,
                                                   int* __restrict__ ecur,
                                                   int* __restrict__ vcur,
                                                   int* __restrict__ ebucket,
                                                   int* __restrict__ vbucket, int nnz) {
    int i = blockIdx.x * 256 + threadIdx.x;
    if (i >= nnz) return;
    int e = edges[i], v = vertex[i];
    ebucket[atomicAdd(&ecur[e], 1)] = v;
    vbucket[atomicAdd(&vcur[v], 1)] = e;
}

// ---------------- edge gather: Xe[e] = mean over entries of P[vertex] ----------------
template<int NO>
__global__ __launch_bounds__(256) void edge_gather(const float* __restrict__ P,
                                                   const int* __restrict__ ebucket,
                                                   const int* __restrict__ eoff,
                                                   const float* __restrict__ inv,
                                                   float* __restrict__ Xe, int E) {
    int wid = (blockIdx.x * 256 + threadIdx.x) >> 6;
    if (wid >= E) return;
    const int lane = threadIdx.x & 63;
    constexpr int FPL = NO / 64;
    const int j1 = eoff[wid + 1];
    int j = eoff[wid];
    float acc0 = 0.0f, acc1 = 0.0f;
    for (; j + 2 <= j1; j += 2) {
        int v0 = ebucket[j], v1 = ebucket[j + 1];
        if constexpr (FPL == 2) {
            float2 a = *reinterpret_cast<const float2*>(P + (size_t)v0 * NO + lane * 2);
            float2 b = *reinterpret_cast<const float2*>(P + (size_t)v1 * NO + lane * 2);
            acc0 += a.x + b.x;
            acc1 += a.y + b.y;
        } else {
            acc0 += P[(size_t)v0 * NO + lane] + P[(size_t)v1 * NO + lane];
        }
    }
    if (j < j1) {
        int v0 = ebucket[j];
        if constexpr (FPL == 2) {
            float2 a = *reinterpret_cast<const float2*>(P + (size_t)v0 * NO + lane * 2);
            acc0 += a.x; acc1 += a.y;
        } else {
            acc0 += P[(size_t)v0 * NO + lane];
        }
    }
    const float s = inv[wid];
    if constexpr (FPL == 2) {
        float2 o; o.x = acc0 * s; o.y = acc1 * s;
        *reinterpret_cast<float2*>(Xe + (size_t)wid * NO + lane * 2) = o;
    } else {
        Xe[(size_t)wid * NO + lane] = acc0 * s;
    }
}

// ---------------- vertex gather + combine ----------------
// P and out may alias (row-local; wave reads only its own P row, at the end).
template<int NO, bool RELU>
__global__ __launch_bounds__(256) void vertex_gather(const float* P,
                                                     const float* __restrict__ Xe,
                                                     const int* __restrict__ vbucket,
                                                     const int* __restrict__ voff,
                                                     const float* __restrict__ eps,
                                                     float* out, int N) {
    int wid = (blockIdx.x * 256 + threadIdx.x) >> 6;
    if (wid >= N) return;
    const int lane = threadIdx.x & 63;
    constexpr int FPL = NO / 64;
    const int j1 = voff[wid + 1];
    int j = voff[wid];
    float acc0 = 0.0f, acc1 = 0.0f;
    for (; j + 2 <= j1; j += 2) {
        int e0 = vbucket[j], e1 = vbucket[j + 1];
        if constexpr (FPL == 2) {
            float2 a = *reinterpret_cast<const float2*>(Xe + (size_t)e0 * NO + lane * 2);
            float2 b = *reinterpret_cast<const float2*>(Xe + (size_t)e1 * NO + lane * 2);
            acc0 += a.x + b.x;
            acc1 += a.y + b.y;
        } else {
            acc0 += Xe[(size_t)e0 * NO + lane] + Xe[(size_t)e1 * NO + lane];
        }
    }
    if (j < j1) {
        int e0 = vbucket[j];
        if constexpr (FPL == 2) {
            float2 a = *reinterpret_cast<const float2*>(Xe + (size_t)e0 * NO + lane * 2);
            acc0 += a.x; acc1 += a.y;
        } else {
            acc0 += Xe[(size_t)e0 * NO + lane];
        }
    }
    const float g = 1.0f + eps[0];
    if constexpr (FPL == 2) {
        float2 p = *reinterpret_cast<const float2*>(P + (size_t)wid * NO + lane * 2);
        float2 o;
        o.x = fmaf(g, p.x, acc0);
        o.y = fmaf(g, p.y, acc1);
        if (RELU) { o.x = fmaxf(o.x, 0.0f); o.y = fmaxf(o.y, 0.0f); }
        *reinterpret_cast<float2*>(out + (size_t)wid * NO + lane * 2) = o;
    } else {
        float p = P[(size_t)wid * NO + lane];
        float o = fmaf(g, p, acc0);
        if (RELU) o = fmaxf(o, 0.0f);
        out[(size_t)wid * NO + lane] = o;
    }
}

extern "C" void kernel_launch(void* const* d_in, const int* in_sizes, int n_in,
                              void* d_out, int out_size, void* d_ws, size_t ws_size,
                              hipStream_t stream) {
    const float* X      = (const float*)d_in[0];
    const int*   vertex = (const int*)d_in[1];
    const int*   edges  = (const int*)d_in[2];
    const float* W1     = (const float*)d_in[3];
    const float* W2     = (const float*)d_in[4];
    const float* W3     = (const float*)d_in[5];
    const float* eps1   = (const float*)d_in[6];
    const float* eps2   = (const float*)d_in[7];
    const float* eps3   = (const float*)d_in[8];

    const int N   = in_sizes[0] / KDIM;   // 100000
    const int nnz = in_sizes[1];          // 800000
    const int E   = NEDGES;               // 20000

    float* outV = (float*)d_out;                 // N*64
    float* outE = outV + (size_t)N * 64;         // E*64

    const int TPB = 256;
    auto blocks = [](long long t) { return (unsigned)((t + 255) / 256); };
    const int nbE = (E + SCAN_CHUNK - 1) / SCAN_CHUNK;
    const int nbV = (N + SCAN_CHUNK - 1) / SCAN_CHUNK;

    // ---------------- workspace carve-up ----------------
    char* ws = (char*)d_ws;
    size_t off = 0;
    auto carve = [&](size_t bytes) { void* p = ws + off; off += (bytes + 255) & ~(size_t)255; return p; };
    // common small tables first
    float* XeBuf   = (float*)carve((size_t)E * 128 * 4);
    float* inv     = (float*)carve((size_t)E * 4);
    int*   ecnt    = (int*)carve((size_t)E * 4);
    int*   eoff    = (int*)carve((size_t)(E + 1) * 4);
    int*   ecur    = (int*)carve((size_t)E * 4);
    int*   vcnt    = (int*)carve((size_t)N * 4);
    int*   voff    = (int*)carve((size_t)(N + 1) * 4);
    int*   vcur    = (int*)carve((size_t)N * 4);
    int*   ebucket = (int*)carve((size_t)nnz * 4);
    int*   vbucket = (int*)carve((size_t)nnz * 4);
    int*   bsumE   = (int*)carve((size_t)1024 * 4);
    int*   bsumV   = (int*)carve((size_t)1024 * 4);
    float* bufA    = (float*)carve((size_t)N * 128 * 4);
    size_t base_need = off + (size_t)N * 128 * 4;          // with bufB
    const bool pingpong = (ws_size >= base_need);
    float* bufB  = pingpong ? (float*)carve((size_t)N * 128 * 4)
                            : (float*)carve((size_t)N * 64 * 4);   // fallback: P3 only

    // ---------------- CSR build (layer-invariant) ----------------
    hipMemsetAsync(ecnt, 0, (size_t)E * 4, stream);
    hipMemsetAsync(vcnt, 0, (size_t)N * 4, stream);
    hist_kernel<<<blocks(nnz), TPB, 0, stream>>>(vertex, edges, ecnt, vcnt, nnz);
    scan_blocksum<<<nbE, TPB, 0, stream>>>(ecnt, bsumE, E);
    scan_blocksum<<<nbV, TPB, 0, stream>>>(vcnt, bsumV, N);
    scan_bsum<<<1, 1024, 0, stream>>>(bsumE, nbE);
    scan_bsum<<<1, 1024, 0, stream>>>(bsumV, nbV);
    scan_final<true><<<nbE, TPB, 0, stream>>>(ecnt, bsumE, eoff, ecur, inv, E);
    scan_final<false><<<nbV, TPB, 0, stream>>>(vcnt, bsumV, voff, vcur, nullptr, N);
    fill_kernel<<<blocks(nnz), TPB, 0, stream>>>(vertex, edges, ecur, vcur, ebucket, vbucket, nnz);

    if (pingpong) {
        // ---- layer 1: X -> P1 in bufA; h1 = comb in bufA ----
        gemm_tile<128><<<dim3(blocks(N), 4), TPB, 0, stream>>>(X, W1, bufA, N);
        edge_gather<128><<<blocks((long long)E * 64), TPB, 0, stream>>>(bufA, ebucket, eoff, inv, XeBuf, E);
        vertex_gather<128, true><<<blocks((long long)N * 64), TPB, 0, stream>>>(bufA, XeBuf, vbucket, voff, eps1, bufA, N);
        // ---- layer 2: h1(bufA) -> P2 in bufB; h2 = comb in bufB ----
        gemm_tile<128><<<dim3(blocks(N), 4), TPB, 0, stream>>>(bufA, W2, bufB, N);
        edge_gather<128><<<blocks((long long)E * 64), TPB, 0, stream>>>(bufB, ebucket, eoff, inv, XeBuf, E);
        vertex_gather<128, true><<<blocks((long long)N * 64), TPB, 0, stream>>>(bufB, XeBuf, vbucket, voff, eps2, bufB, N);
        // ---- layer 3: h2(bufB) -> P3 in bufA; outputs ----
        gemm_tile<64><<<dim3(blocks(N), 2), TPB, 0, stream>>>(bufB, W3, bufA, N);
        edge_gather<64><<<blocks((long long)E * 64), TPB, 0, stream>>>(bufA, ebucket, eoff, inv, outE, E);
        vertex_gather<64, false><<<blocks((long long)N * 64), TPB, 0, stream>>>(bufA, outE, vbucket, voff, eps3, outV, N);
    } else {
        // fallback (R4-proven layout): in-place register-staged GEMM for layer 2
        gemm_tile<128><<<dim3(blocks(N), 4), TPB, 0, stream>>>(X, W1, bufA, N);
        edge_gather<128><<<blocks((long long)E * 64), TPB, 0, stream>>>(bufA, ebucket, eoff, inv, XeBuf, E);
        vertex_gather<128, true><<<blocks((long long)N * 64), TPB, 0, stream>>>(bufA, XeBuf, vbucket, voff, eps1, bufA, N);
        gemm_rows<128><<<blocks(N), TPB, 0, stream>>>(bufA, W2, bufA, N);
        edge_gather<128><<<blocks((long long)E * 64), TPB, 0, stream>>>(bufA, ebucket, eoff, inv, XeBuf, E);
        vertex_gather<128, true><<<blocks((long long)N * 64), TPB, 0, stream>>>(bufA, XeBuf, vbucket, voff, eps2, bufA, N);
        gemm_tile<64><<<dim3(blocks(N), 2), TPB, 0, stream>>>(bufA, W3, bufB, N);
        edge_gather<64><<<blocks((long long)E * 64), TPB, 0, stream>>>(bufB, ebucket, eoff, inv, outE, E);
        vertex_gather<64, false><<<blocks((long long)N * 64), TPB, 0, stream>>>(bufB, outE, vbucket, voff, eps3, outV, N);
    }
}

// Round 6
// 830.031 us; speedup vs baseline: 8.5283x; 1.0434x over previous
//
#include <hip/hip_runtime.h>

static constexpr int KDIM   = 128;   // input feature dim of every layer
static constexpr int NEDGES = 20000;
static constexpr int SCAN_CHUNK = 2048;   // elements per block in hierarchical scan
static constexpr int NRANGE = 8;          // destination ranges for fill (XCD count)

// ---------------- tiled GEMM: P[N,NO] = H[N,128] @ W[128,NO] ----------------
// grid = (row-blocks, NO/32). Block stages a 128x32 W column-panel in LDS
// (16 KB), each thread streams its row and computes 32 outputs. H != P.
template<int NO>
__global__ __launch_bounds__(256) void gemm_tile(const float* __restrict__ H,
                                                 const float* __restrict__ W,
                                                 float* __restrict__ P, int N) {
    constexpr int CB = 32;
    __shared__ float Wl[KDIM * CB];
    const int cb0 = blockIdx.y * CB;
    for (int i = threadIdx.x; i < KDIM * CB; i += 256) {
        int k = i >> 5, j = i & 31;
        Wl[i] = W[k * NO + cb0 + j];
    }
    __syncthreads();
    int row = blockIdx.x * 256 + threadIdx.x;
    if (row >= N) return;
    const float4* xr = reinterpret_cast<const float4*>(H + (size_t)row * KDIM);
    float acc[CB];
#pragma unroll
    for (int j = 0; j < CB; ++j) acc[j] = 0.0f;
#pragma unroll
    for (int k4 = 0; k4 < KDIM / 4; ++k4) {
        const float4 xv = xr[k4];
        const float xs[4] = {xv.x, xv.y, xv.z, xv.w};
#pragma unroll
        for (int kk = 0; kk < 4; ++kk) {
            const float* wrow = &Wl[(k4 * 4 + kk) * CB];
#pragma unroll
            for (int j = 0; j < CB; ++j) acc[j] = fmaf(xs[kk], wrow[j], acc[j]);
        }
    }
    float* pr = P + (size_t)row * NO + cb0;
#pragma unroll
    for (int j = 0; j < CB; j += 4) {
        float4 o;
        o.x = acc[j]; o.y = acc[j + 1]; o.z = acc[j + 2]; o.w = acc[j + 3];
        *reinterpret_cast<float4*>(pr + j) = o;
    }
}

// ---------------- fallback GEMM (in-place safe): register-staged row ----------------
template<int NO>
__global__ __launch_bounds__(256) void gemm_rows(const float* H,
                                                 const float* __restrict__ W,
                                                 float* P, int N) {
    __shared__ float Wl[KDIM * NO];
    for (int i = threadIdx.x; i < KDIM * NO; i += 256) Wl[i] = W[i];
    __syncthreads();
    int row = blockIdx.x * 256 + threadIdx.x;
    if (row >= N) return;
    float4 xr[KDIM / 4];
    const float4* src = reinterpret_cast<const float4*>(H + (size_t)row * KDIM);
#pragma unroll
    for (int i = 0; i < KDIM / 4; ++i) xr[i] = src[i];
    float* pr = P + (size_t)row * NO;
#pragma unroll
    for (int cb = 0; cb < NO / 32; ++cb) {
        float acc[32];
#pragma unroll
        for (int j = 0; j < 32; ++j) acc[j] = 0.0f;
#pragma unroll
        for (int k4 = 0; k4 < KDIM / 4; ++k4) {
            const float xs[4] = {xr[k4].x, xr[k4].y, xr[k4].z, xr[k4].w};
#pragma unroll
            for (int kk = 0; kk < 4; ++kk) {
                const float* wrow = &Wl[(k4 * 4 + kk) * NO + cb * 32];
#pragma unroll
                for (int j = 0; j < 32; ++j) acc[j] = fmaf(xs[kk], wrow[j], acc[j]);
            }
        }
#pragma unroll
        for (int j = 0; j < 32; j += 4) {
            float4 o;
            o.x = acc[j]; o.y = acc[j + 1]; o.z = acc[j + 2]; o.w = acc[j + 3];
            *reinterpret_cast<float4*>(pr + cb * 32 + j) = o;
        }
    }
}

// ---------------- CSR build: histogram, hierarchical scan, fill ----------------
__global__ __launch_bounds__(256) void hist_kernel(const int* __restrict__ vertex,
                                                   const int* __restrict__ edges,
                                                   int* __restrict__ ecnt,
                                                   int* __restrict__ vcnt, int nnz) {
    int i = blockIdx.x * 256 + threadIdx.x;
    if (i >= nnz) return;
    atomicAdd(&ecnt[edges[i]], 1);
    atomicAdd(&vcnt[vertex[i]], 1);
}

__global__ __launch_bounds__(256) void scan_blocksum(const int* __restrict__ cnt,
                                                     int* __restrict__ bsum, int n) {
    __shared__ int sh[256];
    const int base = blockIdx.x * SCAN_CHUNK;
    int s = 0;
#pragma unroll
    for (int k = 0; k < SCAN_CHUNK / 256; ++k) {
        int idx = base + k * 256 + threadIdx.x;
        if (idx < n) s += cnt[idx];
    }
    sh[threadIdx.x] = s;
    __syncthreads();
    for (int d = 128; d > 0; d >>= 1) {
        if (threadIdx.x < d) sh[threadIdx.x] += sh[threadIdx.x + d];
        __syncthreads();
    }
    if (threadIdx.x == 0) bsum[blockIdx.x] = sh[0];
}

__global__ __launch_bounds__(1024) void scan_bsum(int* __restrict__ bsum, int nb) {
    __shared__ int sh[1024];
    const int t = threadIdx.x;
    sh[t] = (t < nb) ? bsum[t] : 0;
    __syncthreads();
    for (int d = 1; d < 1024; d <<= 1) {
        int v = (t >= d) ? sh[t - d] : 0;
        __syncthreads();
        sh[t] += v;
        __syncthreads();
    }
    if (t < nb) bsum[t] = (t == 0) ? 0 : sh[t - 1];
}

template<bool WITH_INV>
__global__ __launch_bounds__(256) void scan_final(const int* __restrict__ cnt,
                                                  const int* __restrict__ bsum,
                                                  int* __restrict__ off,
                                                  int* __restrict__ cur,
                                                  float* __restrict__ inv, int n) {
    __shared__ int sh[256];
    const int t = threadIdx.x;
    const int base = blockIdx.x * SCAN_CHUNK;
    constexpr int EPT = SCAN_CHUNK / 256;   // 8
    int loc[EPT];
    int s = 0;
#pragma unroll
    for (int k = 0; k < EPT; ++k) {
        int idx = base + t * EPT + k;
        loc[k] = (idx < n) ? cnt[idx] : 0;
        s += loc[k];
    }
    sh[t] = s;
    __syncthreads();
    for (int d = 1; d < 256; d <<= 1) {
        int v = (t >= d) ? sh[t - d] : 0;
        __syncthreads();
        sh[t] += v;
        __syncthreads();
    }
    int run = bsum[blockIdx.x] + ((t == 0) ? 0 : sh[t - 1]);
#pragma unroll
    for (int k = 0; k < EPT; ++k) {
        int idx = base + t * EPT + k;
        if (idx < n) {
            off[idx] = run;
            cur[idx] = run;
            if (WITH_INV) inv[idx] = 1.0f / fmaxf((float)loc[k], 1.0f);
            run += loc[k];
            if (idx == n - 1) off[n] = run;
        }
    }
}

// Destination-range-partitioned fill: block b covers entry chunk (b>>3) and
// writes ONLY targets in range (b&7). Dispatch round-robins blocks over the
// 8 XCDs, so each ~400 KB bucket window is written from (mostly) one XCD:
// lines assemble fully in that XCD's L2 and write back once (perf heuristic
// only — correctness never depends on the XCD mapping).
__global__ __launch_bounds__(256) void fill_ranged(const int* __restrict__ vertex,
                                                   const int* __restrict__ edges,
                                                   int* __restrict__ ecur,
                                                   int* __restrict__ vcur,
                                                   int* __restrict__ ebucket,
                                                   int* __restrict__ vbucket,
                                                   int nnz, int E, int N) {
    const int r = blockIdx.x & (NRANGE - 1);
    const int i = (blockIdx.x >> 3) * 256 + threadIdx.x;
    if (i >= nnz) return;
    const int e = edges[i], v = vertex[i];
    const int elo = (int)((long long)r * E / NRANGE);
    const int ehi = (int)((long long)(r + 1) * E / NRANGE);
    const int vlo = (int)((long long)r * N / NRANGE);
    const int vhi = (int)((long long)(r + 1) * N / NRANGE);
    if (e >= elo && e < ehi) ebucket[atomicAdd(&ecur[e], 1)] = v;
    if (v >= vlo && v < vhi) vbucket[atomicAdd(&vcur[v], 1)] = e;
}

// ---------------- edge gather: Xe[e] = mean over entries of P[vertex] ----------------
template<int NO>
__global__ __launch_bounds__(256) void edge_gather(const float* __restrict__ P,
                                                   const int* __restrict__ ebucket,
                                                   const int* __restrict__ eoff,
                                                   const float* __restrict__ inv,
                                                   float* __restrict__ Xe, int E) {
    int wid = (blockIdx.x * 256 + threadIdx.x) >> 6;
    if (wid >= E) return;
    const int lane = threadIdx.x & 63;
    constexpr int FPL = NO / 64;
    const int j1 = eoff[wid + 1];
    int j = eoff[wid];
    float acc0 = 0.0f, acc1 = 0.0f;
    for (; j + 2 <= j1; j += 2) {
        int v0 = ebucket[j], v1 = ebucket[j + 1];
        if constexpr (FPL == 2) {
            float2 a = *reinterpret_cast<const float2*>(P + (size_t)v0 * NO + lane * 2);
            float2 b = *reinterpret_cast<const float2*>(P + (size_t)v1 * NO + lane * 2);
            acc0 += a.x + b.x;
            acc1 += a.y + b.y;
        } else {
            acc0 += P[(size_t)v0 * NO + lane] + P[(size_t)v1 * NO + lane];
        }
    }
    if (j < j1) {
        int v0 = ebucket[j];
        if constexpr (FPL == 2) {
            float2 a = *reinterpret_cast<const float2*>(P + (size_t)v0 * NO + lane * 2);
            acc0 += a.x; acc1 += a.y;
        } else {
            acc0 += P[(size_t)v0 * NO + lane];
        }
    }
    const float s = inv[wid];
    if constexpr (FPL == 2) {
        float2 o; o.x = acc0 * s; o.y = acc1 * s;
        *reinterpret_cast<float2*>(Xe + (size_t)wid * NO + lane * 2) = o;
    } else {
        Xe[(size_t)wid * NO + lane] = acc0 * s;
    }
}

// ---------------- vertex gather + combine ----------------
// P and out may alias (row-local; wave reads only its own P row, at the end).
template<int NO, bool RELU>
__global__ __launch_bounds__(256) void vertex_gather(const float* P,
                                                     const float* __restrict__ Xe,
                                                     const int* __restrict__ vbucket,
                                                     const int* __restrict__ voff,
                                                     const float* __restrict__ eps,
                                                     float* out, int N) {
    int wid = (blockIdx.x * 256 + threadIdx.x) >> 6;
    if (wid >= N) return;
    const int lane = threadIdx.x & 63;
    constexpr int FPL = NO / 64;
    const int j1 = voff[wid + 1];
    int j = voff[wid];
    float acc0 = 0.0f, acc1 = 0.0f;
    for (; j + 2 <= j1; j += 2) {
        int e0 = vbucket[j], e1 = vbucket[j + 1];
        if constexpr (FPL == 2) {
            float2 a = *reinterpret_cast<const float2*>(Xe + (size_t)e0 * NO + lane * 2);
            float2 b = *reinterpret_cast<const float2*>(Xe + (size_t)e1 * NO + lane * 2);
            acc0 += a.x + b.x;
            acc1 += a.y + b.y;
        } else {
            acc0 += Xe[(size_t)e0 * NO + lane] + Xe[(size_t)e1 * NO + lane];
        }
    }
    if (j < j1) {
        int e0 = vbucket[j];
        if constexpr (FPL == 2) {
            float2 a = *reinterpret_cast<const float2*>(Xe + (size_t)e0 * NO + lane * 2);
            acc0 += a.x; acc1 += a.y;
        } else {
            acc0 += Xe[(size_t)e0 * NO + lane];
        }
    }
    const float g = 1.0f + eps[0];
    if constexpr (FPL == 2) {
        float2 p = *reinterpret_cast<const float2*>(P + (size_t)wid * NO + lane * 2);
        float2 o;
        o.x = fmaf(g, p.x, acc0);
        o.y = fmaf(g, p.y, acc1);
        if (RELU) { o.x = fmaxf(o.x, 0.0f); o.y = fmaxf(o.y, 0.0f); }
        *reinterpret_cast<float2*>(out + (size_t)wid * NO + lane * 2) = o;
    } else {
        float p = P[(size_t)wid * NO + lane];
        float o = fmaf(g, p, acc0);
        if (RELU) o = fmaxf(o, 0.0f);
        out[(size_t)wid * NO + lane] = o;
    }
}

extern "C" void kernel_launch(void* const* d_in, const int* in_sizes, int n_in,
                              void* d_out, int out_size, void* d_ws, size_t ws_size,
                              hipStream_t stream) {
    const float* X      = (const float*)d_in[0];
    const int*   vertex = (const int*)d_in[1];
    const int*   edges  = (const int*)d_in[2];
    const float* W1     = (const float*)d_in[3];
    const float* W2     = (const float*)d_in[4];
    const float* W3     = (const float*)d_in[5];
    const float* eps1   = (const float*)d_in[6];
    const float* eps2   = (const float*)d_in[7];
    const float* eps3   = (const float*)d_in[8];

    const int N   = in_sizes[0] / KDIM;   // 100000
    const int nnz = in_sizes[1];          // 800000
    const int E   = NEDGES;               // 20000

    float* outV = (float*)d_out;                 // N*64
    float* outE = outV + (size_t)N * 64;         // E*64

    const int TPB = 256;
    auto blocks = [](long long t) { return (unsigned)((t + 255) / 256); };
    const int nbE = (E + SCAN_CHUNK - 1) / SCAN_CHUNK;
    const int nbV = (N + SCAN_CHUNK - 1) / SCAN_CHUNK;

    // ---------------- workspace carve-up ----------------
    char* ws = (char*)d_ws;
    size_t off = 0;
    auto carve = [&](size_t bytes) { void* p = ws + off; off += (bytes + 255) & ~(size_t)255; return p; };
    float* XeBuf   = (float*)carve((size_t)E * 128 * 4);
    float* inv     = (float*)carve((size_t)E * 4);
    int*   ecnt    = (int*)carve((size_t)E * 4);
    int*   eoff    = (int*)carve((size_t)(E + 1) * 4);
    int*   ecur    = (int*)carve((size_t)E * 4);
    int*   vcnt    = (int*)carve((size_t)N * 4);
    int*   voff    = (int*)carve((size_t)(N + 1) * 4);
    int*   vcur    = (int*)carve((size_t)N * 4);
    int*   ebucket = (int*)carve((size_t)nnz * 4);
    int*   vbucket = (int*)carve((size_t)nnz * 4);
    int*   bsumE   = (int*)carve((size_t)1024 * 4);
    int*   bsumV   = (int*)carve((size_t)1024 * 4);
    float* bufA    = (float*)carve((size_t)N * 128 * 4);
    size_t base_need = off + (size_t)N * 128 * 4;          // with bufB
    const bool pingpong = (ws_size >= base_need);
    float* bufB  = pingpong ? (float*)carve((size_t)N * 128 * 4)
                            : (float*)carve((size_t)N * 64 * 4);   // fallback: P3 only

    // ---------------- CSR build (layer-invariant) ----------------
    hipMemsetAsync(ecnt, 0, (size_t)E * 4, stream);
    hipMemsetAsync(vcnt, 0, (size_t)N * 4, stream);
    hist_kernel<<<blocks(nnz), TPB, 0, stream>>>(vertex, edges, ecnt, vcnt, nnz);
    scan_blocksum<<<nbE, TPB, 0, stream>>>(ecnt, bsumE, E);
    scan_blocksum<<<nbV, TPB, 0, stream>>>(vcnt, bsumV, N);
    scan_bsum<<<1, 1024, 0, stream>>>(bsumE, nbE);
    scan_bsum<<<1, 1024, 0, stream>>>(bsumV, nbV);
    scan_final<true><<<nbE, TPB, 0, stream>>>(ecnt, bsumE, eoff, ecur, inv, E);
    scan_final<false><<<nbV, TPB, 0, stream>>>(vcnt, bsumV, voff, vcur, nullptr, N);
    fill_ranged<<<blocks(nnz) * NRANGE, TPB, 0, stream>>>(vertex, edges, ecur, vcur,
                                                          ebucket, vbucket, nnz, E, N);

    if (pingpong) {
        // ---- layer 1: X -> P1 in bufA; h1 = comb in bufA ----
        gemm_tile<128><<<dim3(blocks(N), 4), TPB, 0, stream>>>(X, W1, bufA, N);
        edge_gather<128><<<blocks((long long)E * 64), TPB, 0, stream>>>(bufA, ebucket, eoff, inv, XeBuf, E);
        vertex_gather<128, true><<<blocks((long long)N * 64), TPB, 0, stream>>>(bufA, XeBuf, vbucket, voff, eps1, bufA, N);
        // ---- layer 2: h1(bufA) -> P2 in bufB; h2 = comb in bufB ----
        gemm_tile<128><<<dim3(blocks(N), 4), TPB, 0, stream>>>(bufA, W2, bufB, N);
        edge_gather<128><<<blocks((long long)E * 64), TPB, 0, stream>>>(bufB, ebucket, eoff, inv, XeBuf, E);
        vertex_gather<128, true><<<blocks((long long)N * 64), TPB, 0, stream>>>(bufB, XeBuf, vbucket, voff, eps2, bufB, N);
        // ---- layer 3: h2(bufB) -> P3 in bufA; outputs ----
        gemm_tile<64><<<dim3(blocks(N), 2), TPB, 0, stream>>>(bufB, W3, bufA, N);
        edge_gather<64><<<blocks((long long)E * 64), TPB, 0, stream>>>(bufA, ebucket, eoff, inv, outE, E);
        vertex_gather<64, false><<<blocks((long long)N * 64), TPB, 0, stream>>>(bufA, outE, vbucket, voff, eps3, outV, N);
    } else {
        // fallback (R4-proven layout): in-place register-staged GEMM for layer 2
        gemm_tile<128><<<dim3(blocks(N), 4), TPB, 0, stream>>>(X, W1, bufA, N);
        edge_gather<128><<<blocks((long long)E * 64), TPB, 0, stream>>>(bufA, ebucket, eoff, inv, XeBuf, E);
        vertex_gather<128, true><<<blocks((long long)N * 64), TPB, 0, stream>>>(bufA, XeBuf, vbucket, voff, eps1, bufA, N);
        gemm_rows<128><<<blocks(N), TPB, 0, stream>>>(bufA, W2, bufA, N);
        edge_gather<128><<<blocks((long long)E * 64), TPB, 0, stream>>>(bufA, ebucket, eoff, inv, XeBuf, E);
        vertex_gather<128, true><<<blocks((long long)N * 64), TPB, 0, stream>>>(bufA, XeBuf, vbucket, voff, eps2, bufA, N);
        gemm_tile<64><<<dim3(blocks(N), 2), TPB, 0, stream>>>(bufA, W3, bufB, N);
        edge_gather<64><<<blocks((long long)E * 64), TPB, 0, stream>>>(bufB, ebucket, eoff, inv, outE, E);
        vertex_gather<64, false><<<blocks((long long)N * 64), TPB, 0, stream>>>(bufB, outE, vbucket, voff, eps3, outV, N);
    }
}

// Round 7
// 731.130 us; speedup vs baseline: 9.6819x; 1.1353x over previous
//
#include <hip/hip_runtime.h>

static constexpr int KDIM   = 128;   // input feature dim of every layer
static constexpr int NEDGES = 20000;
static constexpr int SCAN_CHUNK = 2048;   // elements per block in hierarchical scan
static constexpr int NRANGE = 8;          // destination ranges for fill (XCD count)

// ---------------- tiled GEMM, XCD-swizzled panels ----------------
// P[N,NO] = H[N,128] @ W[128,NO]. Flattened grid of nrb8*NPANEL blocks.
// Decode maps the NPANEL column-panel blocks of one row-block onto the SAME
// XCD (blocks whose ids differ by 8 round-robin to one XCD), so the 128 KB
// H row-panel is HBM-fetched once and L2-hits for the other panels.
// Perf heuristic only: any decode covers each (rb,panel) exactly once.
template<int NO>
__global__ __launch_bounds__(256) void gemm_tile(const float* __restrict__ H,
                                                 const float* __restrict__ W,
                                                 float* __restrict__ P, int N) {
    constexpr int CB = 32;
    constexpr int NPANEL = NO / CB;           // 4 (NO=128) or 2 (NO=64)
    __shared__ float Wl[KDIM * CB];
    const int xcd = blockIdx.x & 7;
    const int idx = blockIdx.x >> 3;
    const int p   = idx & (NPANEL - 1);
    const int rb  = (idx / NPANEL) * 8 + xcd;
    const int cb0 = p * CB;
    for (int i = threadIdx.x; i < KDIM * CB; i += 256) {
        int k = i >> 5, j = i & 31;
        Wl[i] = W[k * NO + cb0 + j];
    }
    __syncthreads();
    int row = rb * 256 + threadIdx.x;
    if (row >= N) return;
    const float4* xr = reinterpret_cast<const float4*>(H + (size_t)row * KDIM);
    float acc[CB];
#pragma unroll
    for (int j = 0; j < CB; ++j) acc[j] = 0.0f;
#pragma unroll
    for (int k4 = 0; k4 < KDIM / 4; ++k4) {
        const float4 xv = xr[k4];
        const float xs[4] = {xv.x, xv.y, xv.z, xv.w};
#pragma unroll
        for (int kk = 0; kk < 4; ++kk) {
            const float* wrow = &Wl[(k4 * 4 + kk) * CB];
#pragma unroll
            for (int j = 0; j < CB; ++j) acc[j] = fmaf(xs[kk], wrow[j], acc[j]);
        }
    }
    float* pr = P + (size_t)row * NO + cb0;
#pragma unroll
    for (int j = 0; j < CB; j += 4) {
        float4 o;
        o.x = acc[j]; o.y = acc[j + 1]; o.z = acc[j + 2]; o.w = acc[j + 3];
        *reinterpret_cast<float4*>(pr + j) = o;
    }
}

// ---------------- fallback GEMM (in-place safe): register-staged row ----------------
template<int NO>
__global__ __launch_bounds__(256) void gemm_rows(const float* H,
                                                 const float* __restrict__ W,
                                                 float* P, int N) {
    __shared__ float Wl[KDIM * NO];
    for (int i = threadIdx.x; i < KDIM * NO; i += 256) Wl[i] = W[i];
    __syncthreads();
    int row = blockIdx.x * 256 + threadIdx.x;
    if (row >= N) return;
    float4 xr[KDIM / 4];
    const float4* src = reinterpret_cast<const float4*>(H + (size_t)row * KDIM);
#pragma unroll
    for (int i = 0; i < KDIM / 4; ++i) xr[i] = src[i];
    float* pr = P + (size_t)row * NO;
#pragma unroll
    for (int cb = 0; cb < NO / 32; ++cb) {
        float acc[32];
#pragma unroll
        for (int j = 0; j < 32; ++j) acc[j] = 0.0f;
#pragma unroll
        for (int k4 = 0; k4 < KDIM / 4; ++k4) {
            const float xs[4] = {xr[k4].x, xr[k4].y, xr[k4].z, xr[k4].w};
#pragma unroll
            for (int kk = 0; kk < 4; ++kk) {
                const float* wrow = &Wl[(k4 * 4 + kk) * NO + cb * 32];
#pragma unroll
                for (int j = 0; j < 32; ++j) acc[j] = fmaf(xs[kk], wrow[j], acc[j]);
            }
        }
#pragma unroll
        for (int j = 0; j < 32; j += 4) {
            float4 o;
            o.x = acc[j]; o.y = acc[j + 1]; o.z = acc[j + 2]; o.w = acc[j + 3];
            *reinterpret_cast<float4*>(pr + cb * 32 + j) = o;
        }
    }
}

// ---------------- CSR build: histogram, hierarchical scan, fill ----------------
__global__ __launch_bounds__(256) void hist_kernel(const int* __restrict__ vertex,
                                                   const int* __restrict__ edges,
                                                   int* __restrict__ ecnt,
                                                   int* __restrict__ vcnt, int nnz) {
    int i = blockIdx.x * 256 + threadIdx.x;
    if (i >= nnz) return;
    atomicAdd(&ecnt[edges[i]], 1);
    atomicAdd(&vcnt[vertex[i]], 1);
}

__global__ __launch_bounds__(256) void scan_blocksum(const int* __restrict__ cnt,
                                                     int* __restrict__ bsum, int n) {
    __shared__ int sh[256];
    const int base = blockIdx.x * SCAN_CHUNK;
    int s = 0;
#pragma unroll
    for (int k = 0; k < SCAN_CHUNK / 256; ++k) {
        int idx = base + k * 256 + threadIdx.x;
        if (idx < n) s += cnt[idx];
    }
    sh[threadIdx.x] = s;
    __syncthreads();
    for (int d = 128; d > 0; d >>= 1) {
        if (threadIdx.x < d) sh[threadIdx.x] += sh[threadIdx.x + d];
        __syncthreads();
    }
    if (threadIdx.x == 0) bsum[blockIdx.x] = sh[0];
}

__global__ __launch_bounds__(1024) void scan_bsum(int* __restrict__ bsum, int nb) {
    __shared__ int sh[1024];
    const int t = threadIdx.x;
    sh[t] = (t < nb) ? bsum[t] : 0;
    __syncthreads();
    for (int d = 1; d < 1024; d <<= 1) {
        int v = (t >= d) ? sh[t - d] : 0;
        __syncthreads();
        sh[t] += v;
        __syncthreads();
    }
    if (t < nb) bsum[t] = (t == 0) ? 0 : sh[t - 1];
}

template<bool WITH_INV>
__global__ __launch_bounds__(256) void scan_final(const int* __restrict__ cnt,
                                                  const int* __restrict__ bsum,
                                                  int* __restrict__ off,
                                                  int* __restrict__ cur,
                                                  float* __restrict__ inv, int n) {
    __shared__ int sh[256];
    const int t = threadIdx.x;
    const int base = blockIdx.x * SCAN_CHUNK;
    constexpr int EPT = SCAN_CHUNK / 256;   // 8
    int loc[EPT];
    int s = 0;
#pragma unroll
    for (int k = 0; k < EPT; ++k) {
        int idx = base + t * EPT + k;
        loc[k] = (idx < n) ? cnt[idx] : 0;
        s += loc[k];
    }
    sh[t] = s;
    __syncthreads();
    for (int d = 1; d < 256; d <<= 1) {
        int v = (t >= d) ? sh[t - d] : 0;
        __syncthreads();
        sh[t] += v;
        __syncthreads();
    }
    int run = bsum[blockIdx.x] + ((t == 0) ? 0 : sh[t - 1]);
#pragma unroll
    for (int k = 0; k < EPT; ++k) {
        int idx = base + t * EPT + k;
        if (idx < n) {
            off[idx] = run;
            cur[idx] = run;
            if (WITH_INV) inv[idx] = 1.0f / fmaxf((float)loc[k], 1.0f);
            run += loc[k];
            if (idx == n - 1) off[n] = run;
        }
    }
}

// Destination-range-partitioned fill (see R6 notes): block b covers entry
// chunk (b>>3) and writes ONLY targets in range (b&7) -> each bucket window
// is written from (mostly) one XCD, lines assemble in its L2.
__global__ __launch_bounds__(256) void fill_ranged(const int* __restrict__ vertex,
                                                   const int* __restrict__ edges,
                                                   int* __restrict__ ecur,
                                                   int* __restrict__ vcur,
                                                   int* __restrict__ ebucket,
                                                   int* __restrict__ vbucket,
                                                   int nnz, int E, int N) {
    const int r = blockIdx.x & (NRANGE - 1);
    const int i = (blockIdx.x >> 3) * 256 + threadIdx.x;
    if (i >= nnz) return;
    const int e = edges[i], v = vertex[i];
    const int elo = (int)((long long)r * E / NRANGE);
    const int ehi = (int)((long long)(r + 1) * E / NRANGE);
    const int vlo = (int)((long long)r * N / NRANGE);
    const int vhi = (int)((long long)(r + 1) * N / NRANGE);
    if (e >= elo && e < ehi) ebucket[atomicAdd(&ecur[e], 1)] = v;
    if (v >= vlo && v < vhi) vbucket[atomicAdd(&vcur[v], 1)] = e;
}

// ---------------- edge gather: Xe[e] = mean over entries of P[vertex] ----------------
template<int NO>
__global__ __launch_bounds__(256) void edge_gather(const float* __restrict__ P,
                                                   const int* __restrict__ ebucket,
                                                   const int* __restrict__ eoff,
                                                   const float* __restrict__ inv,
                                                   float* __restrict__ Xe, int E) {
    int wid = (blockIdx.x * 256 + threadIdx.x) >> 6;
    if (wid >= E) return;
    const int lane = threadIdx.x & 63;
    constexpr int FPL = NO / 64;
    const int j1 = eoff[wid + 1];
    int j = eoff[wid];
    float acc0 = 0.0f, acc1 = 0.0f;
    for (; j + 2 <= j1; j += 2) {
        int v0 = ebucket[j], v1 = ebucket[j + 1];
        if constexpr (FPL == 2) {
            float2 a = *reinterpret_cast<const float2*>(P + (size_t)v0 * NO + lane * 2);
            float2 b = *reinterpret_cast<const float2*>(P + (size_t)v1 * NO + lane * 2);
            acc0 += a.x + b.x;
            acc1 += a.y + b.y;
        } else {
            acc0 += P[(size_t)v0 * NO + lane] + P[(size_t)v1 * NO + lane];
        }
    }
    if (j < j1) {
        int v0 = ebucket[j];
        if constexpr (FPL == 2) {
            float2 a = *reinterpret_cast<const float2*>(P + (size_t)v0 * NO + lane * 2);
            acc0 += a.x; acc1 += a.y;
        } else {
            acc0 += P[(size_t)v0 * NO + lane];
        }
    }
    const float s = inv[wid];
    if constexpr (FPL == 2) {
        float2 o; o.x = acc0 * s; o.y = acc1 * s;
        *reinterpret_cast<float2*>(Xe + (size_t)wid * NO + lane * 2) = o;
    } else {
        Xe[(size_t)wid * NO + lane] = acc0 * s;
    }
}

// ---------------- vertex gather + combine ----------------
// P and out may alias (row-local; wave reads only its own P row, at the end).
template<int NO, bool RELU>
__global__ __launch_bounds__(256) void vertex_gather(const float* P,
                                                     const float* __restrict__ Xe,
                                                     const int* __restrict__ vbucket,
                                                     const int* __restrict__ voff,
                                                     const float* __restrict__ eps,
                                                     float* out, int N) {
    int wid = (blockIdx.x * 256 + threadIdx.x) >> 6;
    if (wid >= N) return;
    const int lane = threadIdx.x & 63;
    constexpr int FPL = NO / 64;
    const int j1 = voff[wid + 1];
    int j = voff[wid];
    float acc0 = 0.0f, acc1 = 0.0f;
    for (; j + 2 <= j1; j += 2) {
        int e0 = vbucket[j], e1 = vbucket[j + 1];
        if constexpr (FPL == 2) {
            float2 a = *reinterpret_cast<const float2*>(Xe + (size_t)e0 * NO + lane * 2);
            float2 b = *reinterpret_cast<const float2*>(Xe + (size_t)e1 * NO + lane * 2);
            acc0 += a.x + b.x;
            acc1 += a.y + b.y;
        } else {
            acc0 += Xe[(size_t)e0 * NO + lane] + Xe[(size_t)e1 * NO + lane];
        }
    }
    if (j < j1) {
        int e0 = vbucket[j];
        if constexpr (FPL == 2) {
            float2 a = *reinterpret_cast<const float2*>(Xe + (size_t)e0 * NO + lane * 2);
            acc0 += a.x; acc1 += a.y;
        } else {
            acc0 += Xe[(size_t)e0 * NO + lane];
        }
    }
    const float g = 1.0f + eps[0];
    if constexpr (FPL == 2) {
        float2 p = *reinterpret_cast<const float2*>(P + (size_t)wid * NO + lane * 2);
        float2 o;
        o.x = fmaf(g, p.x, acc0);
        o.y = fmaf(g, p.y, acc1);
        if (RELU) { o.x = fmaxf(o.x, 0.0f); o.y = fmaxf(o.y, 0.0f); }
        *reinterpret_cast<float2*>(out + (size_t)wid * NO + lane * 2) = o;
    } else {
        float p = P[(size_t)wid * NO + lane];
        float o = fmaf(g, p, acc0);
        if (RELU) o = fmaxf(o, 0.0f);
        out[(size_t)wid * NO + lane] = o;
    }
}

extern "C" void kernel_launch(void* const* d_in, const int* in_sizes, int n_in,
                              void* d_out, int out_size, void* d_ws, size_t ws_size,
                              hipStream_t stream) {
    const float* X      = (const float*)d_in[0];
    const int*   vertex = (const int*)d_in[1];
    const int*   edges  = (const int*)d_in[2];
    const float* W1     = (const float*)d_in[3];
    const float* W2     = (const float*)d_in[4];
    const float* W3     = (const float*)d_in[5];
    const float* eps1   = (const float*)d_in[6];
    const float* eps2   = (const float*)d_in[7];
    const float* eps3   = (const float*)d_in[8];

    const int N   = in_sizes[0] / KDIM;   // 100000
    const int nnz = in_sizes[1];          // 800000
    const int E   = NEDGES;               // 20000

    float* outV = (float*)d_out;                 // N*64
    float* outE = outV + (size_t)N * 64;         // E*64

    const int TPB = 256;
    auto blocks = [](long long t) { return (unsigned)((t + 255) / 256); };
    const int nbE = (E + SCAN_CHUNK - 1) / SCAN_CHUNK;
    const int nbV = (N + SCAN_CHUNK - 1) / SCAN_CHUNK;
    const int nrb  = (N + 255) / 256;          // 391 row-blocks
    const int nrb8 = ((nrb + 7) / 8) * 8;      // padded to 392 for the swizzle
    const unsigned g128 = (unsigned)(nrb8 * 4);  // NO=128: 4 panels
    const unsigned g64  = (unsigned)(nrb8 * 2);  // NO=64 : 2 panels

    // ---------------- workspace carve-up ----------------
    char* ws = (char*)d_ws;
    size_t off = 0;
    auto carve = [&](size_t bytes) { void* p = ws + off; off += (bytes + 255) & ~(size_t)255; return p; };
    float* XeBuf   = (float*)carve((size_t)E * 128 * 4);
    float* inv     = (float*)carve((size_t)E * 4);
    int*   ecnt    = (int*)carve((size_t)E * 4);
    int*   eoff    = (int*)carve((size_t)(E + 1) * 4);
    int*   ecur    = (int*)carve((size_t)E * 4);
    int*   vcnt    = (int*)carve((size_t)N * 4);
    int*   voff    = (int*)carve((size_t)(N + 1) * 4);
    int*   vcur    = (int*)carve((size_t)N * 4);
    int*   ebucket = (int*)carve((size_t)nnz * 4);
    int*   vbucket = (int*)carve((size_t)nnz * 4);
    int*   bsumE   = (int*)carve((size_t)1024 * 4);
    int*   bsumV   = (int*)carve((size_t)1024 * 4);
    float* bufA    = (float*)carve((size_t)N * 128 * 4);
    size_t base_need = off + (size_t)N * 128 * 4;          // with bufB
    const bool pingpong = (ws_size >= base_need);
    float* bufB  = pingpong ? (float*)carve((size_t)N * 128 * 4)
                            : (float*)carve((size_t)N * 64 * 4);   // fallback: P3 only

    // ---------------- CSR build (layer-invariant) ----------------
    hipMemsetAsync(ecnt, 0, (size_t)E * 4, stream);
    hipMemsetAsync(vcnt, 0, (size_t)N * 4, stream);
    hist_kernel<<<blocks(nnz), TPB, 0, stream>>>(vertex, edges, ecnt, vcnt, nnz);
    scan_blocksum<<<nbE, TPB, 0, stream>>>(ecnt, bsumE, E);
    scan_blocksum<<<nbV, TPB, 0, stream>>>(vcnt, bsumV, N);
    scan_bsum<<<1, 1024, 0, stream>>>(bsumE, nbE);
    scan_bsum<<<1, 1024, 0, stream>>>(bsumV, nbV);
    scan_final<true><<<nbE, TPB, 0, stream>>>(ecnt, bsumE, eoff, ecur, inv, E);
    scan_final<false><<<nbV, TPB, 0, stream>>>(vcnt, bsumV, voff, vcur, nullptr, N);
    fill_ranged<<<blocks(nnz) * NRANGE, TPB, 0, stream>>>(vertex, edges, ecur, vcur,
                                                          ebucket, vbucket, nnz, E, N);

    if (pingpong) {
        // ---- layer 1: X -> P1 in bufA; h1 = comb in bufA ----
        gemm_tile<128><<<g128, TPB, 0, stream>>>(X, W1, bufA, N);
        edge_gather<128><<<blocks((long long)E * 64), TPB, 0, stream>>>(bufA, ebucket, eoff, inv, XeBuf, E);
        vertex_gather<128, true><<<blocks((long long)N * 64), TPB, 0, stream>>>(bufA, XeBuf, vbucket, voff, eps1, bufA, N);
        // ---- layer 2: h1(bufA) -> P2 in bufB; h2 = comb in bufB ----
        gemm_tile<128><<<g128, TPB, 0, stream>>>(bufA, W2, bufB, N);
        edge_gather<128><<<blocks((long long)E * 64), TPB, 0, stream>>>(bufB, ebucket, eoff, inv, XeBuf, E);
        vertex_gather<128, true><<<blocks((long long)N * 64), TPB, 0, stream>>>(bufB, XeBuf, vbucket, voff, eps2, bufB, N);
        // ---- layer 3: h2(bufB) -> P3 in bufA; outputs ----
        gemm_tile<64><<<g64, TPB, 0, stream>>>(bufB, W3, bufA, N);
        edge_gather<64><<<blocks((long long)E * 64), TPB, 0, stream>>>(bufA, ebucket, eoff, inv, outE, E);
        vertex_gather<64, false><<<blocks((long long)N * 64), TPB, 0, stream>>>(bufA, outE, vbucket, voff, eps3, outV, N);
    } else {
        // fallback (R4-proven layout): in-place register-staged GEMM for layer 2
        gemm_tile<128><<<g128, TPB, 0, stream>>>(X, W1, bufA, N);
        edge_gather<128><<<blocks((long long)E * 64), TPB, 0, stream>>>(bufA, ebucket, eoff, inv, XeBuf, E);
        vertex_gather<128, true><<<blocks((long long)N * 64), TPB, 0, stream>>>(bufA, XeBuf, vbucket, voff, eps1, bufA, N);
        gemm_rows<128><<<blocks(N), TPB, 0, stream>>>(bufA, W2, bufA, N);
        edge_gather<128><<<blocks((long long)E * 64), TPB, 0, stream>>>(bufA, ebucket, eoff, inv, XeBuf, E);
        vertex_gather<128, true><<<blocks((long long)N * 64), TPB, 0, stream>>>(bufA, XeBuf, vbucket, voff, eps2, bufA, N);
        gemm_tile<64><<<g64, TPB, 0, stream>>>(bufA, W3, bufB, N);
        edge_gather<64><<<blocks((long long)E * 64), TPB, 0, stream>>>(bufB, ebucket, eoff, inv, outE, E);
        vertex_gather<64, false><<<blocks((long long)N * 64), TPB, 0, stream>>>(bufB, outE, vbucket, voff, eps3, outV, N);
    }
}